// Round 1
// baseline (1361.158 us; speedup 1.0000x reference)
//
#include <hip/hip_runtime.h>
#include <hip/hip_bf16.h>

#define T 2048
#define H 2560
#define NE 8
#define ITXT 1536
#define IIMG 512
#define ISH 3072
#define CAP 2048

using bf16 = __hip_bfloat16;
typedef short short8 __attribute__((ext_vector_type(8)));
typedef float float4v __attribute__((ext_vector_type(4)));

// ---- workspace layout (bytes) ----
static constexpr size_t OFF_XBF  = 0;                                   // bf16[T*H]
static constexpr size_t OFF_CNT  = OFF_XBF + (size_t)T * H * 2;         // int[32]
static constexpr size_t OFF_TOK  = OFF_CNT + 128;                       // int[17][CAP]
static constexpr size_t OFF_WTS  = OFF_TOK + (size_t)17 * CAP * 4;      // float[17][CAP]
static constexpr size_t OFF_HTXT = OFF_WTS + (size_t)17 * CAP * 4;      // bf16[8][CAP][ITXT]
static constexpr size_t OFF_HIMG = OFF_HTXT + (size_t)NE * CAP * ITXT * 2;
static constexpr size_t OFF_HSH  = OFF_HIMG + (size_t)NE * CAP * IIMG * 2;

__device__ __forceinline__ unsigned short f2bf(float f) {
    bf16 b = __float2bfloat16(f);
    unsigned short u;
    __builtin_memcpy(&u, &b, 2);
    return u;
}

// ---- cast x to bf16 + init shared bucket ----
__global__ void k_cast_init(const float* __restrict__ x, bf16* __restrict__ xb,
                            int* __restrict__ counts, int* __restrict__ toks,
                            float* __restrict__ wts) {
    int i = blockIdx.x * blockDim.x + threadIdx.x;   // < T*H/4
    float4 v = ((const float4*)x)[i];
    ushort4 p;
    p.x = f2bf(v.x); p.y = f2bf(v.y); p.z = f2bf(v.z); p.w = f2bf(v.w);
    *(ushort4*)(xb + 4 * (size_t)i) = p;
    if (i < CAP) { toks[16 * CAP + i] = i; wts[16 * CAP + i] = 1.0f; }
    if (i == 0) counts[16] = T;
}

// ---- router: one wave per token ----
__global__ void k_router(const float* __restrict__ x, const int* __restrict__ vmask,
                         const float* __restrict__ tg, const float* __restrict__ ig,
                         int* __restrict__ counts, int* __restrict__ toks,
                         float* __restrict__ wts) {
    int wave = threadIdx.x >> 6;
    int lane = threadIdx.x & 63;
    int t = blockIdx.x * 4 + wave;
    if (t >= T) return;
    bool vis = vmask[t] != 0;
    const float* gw = vis ? ig : tg;
    const float* xr = x + (size_t)t * H;
    float logits[NE];
#pragma unroll
    for (int e = 0; e < NE; ++e) {
        const float* g = gw + (size_t)e * H;
        double s = 0.0;
        for (int h = lane; h < H; h += 64) s += (double)xr[h] * (double)g[h];
#pragma unroll
        for (int off = 32; off > 0; off >>= 1) s += __shfl_xor(s, off);
        logits[e] = (float)s;
    }
    if (lane == 0) {
        int e1 = 0;
#pragma unroll
        for (int e = 1; e < NE; ++e) if (logits[e] > logits[e1]) e1 = e;
        int e2 = -1;
#pragma unroll
        for (int e = 0; e < NE; ++e)
            if (e != e1 && (e2 < 0 || logits[e] > logits[e2])) e2 = e;
        float w1 = 1.0f / (1.0f + expf(logits[e2] - logits[e1]));
        float w2 = 1.0f - w1;
        int b = vis ? 8 : 0;
        int s1 = atomicAdd(&counts[b + e1], 1);
        toks[(b + e1) * CAP + s1] = t; wts[(b + e1) * CAP + s1] = w1;
        int s2 = atomicAdd(&counts[b + e2], 1);
        toks[(b + e2) * CAP + s2] = t; wts[(b + e2) * CAP + s2] = w2;
    }
}

// ---- grouped GEMM tiles ----
#define MT 128
#define NT 64
#define BK 32
#define LSTR 40   // BK + 8 pad, bf16 elems

// h = silu(A*Bg) * (A*Bu); A gathered from x_bf via token list
__global__ __launch_bounds__(256) void k_gateup(
    const float* __restrict__ Bg, const float* __restrict__ Bu,
    int ldb, int K, size_t wstride,
    const bf16* __restrict__ A, int lda,
    const int* __restrict__ counts, const int* __restrict__ toks, int bucket_base,
    bf16* __restrict__ hout, int hstr, size_t hestride) {
    int e = blockIdx.z;
    int bucket = bucket_base + e;
    int cnt = counts[bucket];
    int m0 = blockIdx.y * MT;
    if (m0 >= cnt) return;
    int n0 = blockIdx.x * NT;
    const int* tk = toks + (size_t)bucket * CAP + m0;
    const float* bg = Bg + (size_t)e * wstride;
    const float* bu = Bu + (size_t)e * wstride;

    __shared__ bf16 As[MT][LSTR];
    __shared__ bf16 Bs[2][NT][LSTR];

    int tid = threadIdx.x;
    int lane = tid & 63;
    int wv = tid >> 6;
    int wm = wv >> 1, wn = wv & 1;

    float4v accg[4][2], accu[4][2];
#pragma unroll
    for (int i = 0; i < 4; ++i)
#pragma unroll
        for (int j = 0; j < 2; ++j) { accg[i][j] = (float4v)0.0f; accu[i][j] = (float4v)0.0f; }

    int ar = tid >> 2;            // A stage: row 0..63 (+64)
    int akc = (tid & 3) << 3;     // k elem offset 0,8,16,24
    int bn = (tid & 15) << 2;     // B stage: n offset
    int bk = (tid >> 4) << 1;     // B stage: k row 0..30
    int fr = lane & 15;           // frag row
    int fk = (lane >> 4) << 3;    // frag k offset

    for (int k0 = 0; k0 < K; k0 += BK) {
        __syncthreads();
        // stage A (gathered, zero-fill beyond count)
#pragma unroll
        for (int h = 0; h < 2; ++h) {
            int rr = ar + h * 64;
            uint4 v = make_uint4(0, 0, 0, 0);
            if (m0 + rr < cnt) {
                int tok = tk[rr];
                v = *(const uint4*)(A + (size_t)tok * lda + k0 + akc);
            }
            *(uint4*)&As[rr][akc] = v;
        }
        // stage B: fp32 -> bf16, transpose to [n][k]
        {
            const float* s0 = bg + (size_t)(k0 + bk) * ldb + n0 + bn;
            float4 v0 = *(const float4*)s0;
            float4 v1 = *(const float4*)(s0 + ldb);
            *(unsigned*)&Bs[0][bn + 0][bk] = (unsigned)f2bf(v0.x) | ((unsigned)f2bf(v1.x) << 16);
            *(unsigned*)&Bs[0][bn + 1][bk] = (unsigned)f2bf(v0.y) | ((unsigned)f2bf(v1.y) << 16);
            *(unsigned*)&Bs[0][bn + 2][bk] = (unsigned)f2bf(v0.z) | ((unsigned)f2bf(v1.z) << 16);
            *(unsigned*)&Bs[0][bn + 3][bk] = (unsigned)f2bf(v0.w) | ((unsigned)f2bf(v1.w) << 16);
            const float* s1 = bu + (size_t)(k0 + bk) * ldb + n0 + bn;
            float4 u0 = *(const float4*)s1;
            float4 u1 = *(const float4*)(s1 + ldb);
            *(unsigned*)&Bs[1][bn + 0][bk] = (unsigned)f2bf(u0.x) | ((unsigned)f2bf(u1.x) << 16);
            *(unsigned*)&Bs[1][bn + 1][bk] = (unsigned)f2bf(u0.y) | ((unsigned)f2bf(u1.y) << 16);
            *(unsigned*)&Bs[1][bn + 2][bk] = (unsigned)f2bf(u0.z) | ((unsigned)f2bf(u1.z) << 16);
            *(unsigned*)&Bs[1][bn + 3][bk] = (unsigned)f2bf(u0.w) | ((unsigned)f2bf(u1.w) << 16);
        }
        __syncthreads();
        short8 af[4], bgf[2], buf_[2];
#pragma unroll
        for (int i = 0; i < 4; ++i) af[i] = *(const short8*)&As[wm * 64 + i * 16 + fr][fk];
#pragma unroll
        for (int j = 0; j < 2; ++j) {
            bgf[j]  = *(const short8*)&Bs[0][wn * 32 + j * 16 + fr][fk];
            buf_[j] = *(const short8*)&Bs[1][wn * 32 + j * 16 + fr][fk];
        }
#pragma unroll
        for (int i = 0; i < 4; ++i)
#pragma unroll
            for (int j = 0; j < 2; ++j) {
                accg[i][j] = __builtin_amdgcn_mfma_f32_16x16x32_bf16(af[i], bgf[j],  accg[i][j], 0, 0, 0);
                accu[i][j] = __builtin_amdgcn_mfma_f32_16x16x32_bf16(af[i], buf_[j], accu[i][j], 0, 0, 0);
            }
    }
    // epilogue: silu(g)*u -> bf16 h
    int rbase = (lane >> 4) << 2;
    int cc = lane & 15;
    bf16* hb = hout + hestride * (size_t)e;
#pragma unroll
    for (int i = 0; i < 4; ++i)
#pragma unroll
        for (int j = 0; j < 2; ++j)
#pragma unroll
            for (int r = 0; r < 4; ++r) {
                int ml = m0 + wm * 64 + i * 16 + rbase + r;
                if (ml < cnt) {
                    int col = n0 + wn * 32 + j * 16 + cc;
                    float g = accg[i][j][r], u = accu[i][j][r];
                    float hv = g / (1.0f + expf(-g)) * u;
                    hb[(size_t)ml * hstr + col] = __float2bfloat16(hv);
                }
            }
}

// y = (h * Bd) * w[row]; atomicAdd into out[tok]
__global__ __launch_bounds__(256) void k_down(
    const float* __restrict__ Bw, int ldb, int K, size_t wstride,
    const bf16* __restrict__ Abase, size_t aestride, int lda,
    const int* __restrict__ counts, const int* __restrict__ toks,
    const float* __restrict__ wts, int bucket_base,
    float* __restrict__ out) {
    int e = blockIdx.z;
    int bucket = bucket_base + e;
    int cnt = counts[bucket];
    int m0 = blockIdx.y * MT;
    if (m0 >= cnt) return;
    int n0 = blockIdx.x * NT;
    const float* bw = Bw + (size_t)e * wstride;
    const bf16* Ab = Abase + (size_t)e * aestride;

    __shared__ bf16 As[MT][LSTR];
    __shared__ bf16 Bs[NT][LSTR];

    int tid = threadIdx.x;
    int lane = tid & 63;
    int wv = tid >> 6;
    int wm = wv >> 1, wn = wv & 1;

    float4v acc[4][2];
#pragma unroll
    for (int i = 0; i < 4; ++i)
#pragma unroll
        for (int j = 0; j < 2; ++j) acc[i][j] = (float4v)0.0f;

    int ar = tid >> 2;
    int akc = (tid & 3) << 3;
    int bn = (tid & 15) << 2;
    int bk = (tid >> 4) << 1;
    int fr = lane & 15;
    int fk = (lane >> 4) << 3;

    for (int k0 = 0; k0 < K; k0 += BK) {
        __syncthreads();
#pragma unroll
        for (int h = 0; h < 2; ++h) {
            int rr = ar + h * 64;
            uint4 v = make_uint4(0, 0, 0, 0);
            if (m0 + rr < cnt)
                v = *(const uint4*)(Ab + (size_t)(m0 + rr) * lda + k0 + akc);
            *(uint4*)&As[rr][akc] = v;
        }
        {
            const float* s0 = bw + (size_t)(k0 + bk) * ldb + n0 + bn;
            float4 v0 = *(const float4*)s0;
            float4 v1 = *(const float4*)(s0 + ldb);
            *(unsigned*)&Bs[bn + 0][bk] = (unsigned)f2bf(v0.x) | ((unsigned)f2bf(v1.x) << 16);
            *(unsigned*)&Bs[bn + 1][bk] = (unsigned)f2bf(v0.y) | ((unsigned)f2bf(v1.y) << 16);
            *(unsigned*)&Bs[bn + 2][bk] = (unsigned)f2bf(v0.z) | ((unsigned)f2bf(v1.z) << 16);
            *(unsigned*)&Bs[bn + 3][bk] = (unsigned)f2bf(v0.w) | ((unsigned)f2bf(v1.w) << 16);
        }
        __syncthreads();
        short8 af[4], bf_[2];
#pragma unroll
        for (int i = 0; i < 4; ++i) af[i] = *(const short8*)&As[wm * 64 + i * 16 + fr][fk];
#pragma unroll
        for (int j = 0; j < 2; ++j) bf_[j] = *(const short8*)&Bs[wn * 32 + j * 16 + fr][fk];
#pragma unroll
        for (int i = 0; i < 4; ++i)
#pragma unroll
            for (int j = 0; j < 2; ++j)
                acc[i][j] = __builtin_amdgcn_mfma_f32_16x16x32_bf16(af[i], bf_[j], acc[i][j], 0, 0, 0);
    }
    int rbase = (lane >> 4) << 2;
    int cc = lane & 15;
    const int* tkl = toks + (size_t)bucket * CAP;
    const float* wl = wts + (size_t)bucket * CAP;
#pragma unroll
    for (int i = 0; i < 4; ++i)
#pragma unroll
        for (int j = 0; j < 2; ++j)
#pragma unroll
            for (int r = 0; r < 4; ++r) {
                int ml = m0 + wm * 64 + i * 16 + rbase + r;
                if (ml < cnt) {
                    int col = n0 + wn * 32 + j * 16 + cc;
                    int tok = tkl[ml];
                    atomicAdd(&out[(size_t)tok * H + col], acc[i][j][r] * wl[ml]);
                }
            }
}

extern "C" void kernel_launch(void* const* d_in, const int* in_sizes, int n_in,
                              void* d_out, int out_size, void* d_ws, size_t ws_size,
                              hipStream_t stream) {
    const float* x    = (const float*)d_in[0];
    const int*   vm   = (const int*)d_in[1];
    const float* tg   = (const float*)d_in[2];
    const float* twg  = (const float*)d_in[3];
    const float* twu  = (const float*)d_in[4];
    const float* twd  = (const float*)d_in[5];
    const float* ig   = (const float*)d_in[6];
    const float* iwg  = (const float*)d_in[7];
    const float* iwu  = (const float*)d_in[8];
    const float* iwd  = (const float*)d_in[9];
    const float* swg  = (const float*)d_in[10];
    const float* swu  = (const float*)d_in[11];
    const float* swd  = (const float*)d_in[12];
    float* out = (float*)d_out;
    char* ws = (char*)d_ws;

    bf16* xb     = (bf16*)(ws + OFF_XBF);
    int*  counts = (int*)(ws + OFF_CNT);
    int*  toks   = (int*)(ws + OFF_TOK);
    float* wtsp  = (float*)(ws + OFF_WTS);
    bf16* htxt   = (bf16*)(ws + OFF_HTXT);
    bf16* himg   = (bf16*)(ws + OFF_HIMG);
    bf16* hsh    = (bf16*)(ws + OFF_HSH);

    hipMemsetAsync(counts, 0, 128, stream);
    hipMemsetAsync(out, 0, (size_t)T * H * sizeof(float), stream);

    k_cast_init<<<dim3((T * H / 4) / 256), dim3(256), 0, stream>>>(x, xb, counts, toks, wtsp);
    k_router<<<dim3(T / 4), dim3(256), 0, stream>>>(x, vm, tg, ig, counts, toks, wtsp);

    // gate+up: text / image / shared
    k_gateup<<<dim3(ITXT / NT, CAP / MT, NE), dim3(256), 0, stream>>>(
        twg, twu, ITXT, H, (size_t)H * ITXT, xb, H, counts, toks, 0,
        htxt, ITXT, (size_t)CAP * ITXT);
    k_gateup<<<dim3(IIMG / NT, CAP / MT, NE), dim3(256), 0, stream>>>(
        iwg, iwu, IIMG, H, (size_t)H * IIMG, xb, H, counts, toks, 8,
        himg, IIMG, (size_t)CAP * IIMG);
    k_gateup<<<dim3(ISH / NT, CAP / MT, 1), dim3(256), 0, stream>>>(
        swg, swu, ISH, H, 0, xb, H, counts, toks, 16,
        hsh, ISH, 0);

    // down: text / image / shared
    k_down<<<dim3(H / NT, CAP / MT, NE), dim3(256), 0, stream>>>(
        twd, H, ITXT, (size_t)ITXT * H, htxt, (size_t)CAP * ITXT, ITXT,
        counts, toks, wtsp, 0, out);
    k_down<<<dim3(H / NT, CAP / MT, NE), dim3(256), 0, stream>>>(
        iwd, H, IIMG, (size_t)IIMG * H, himg, (size_t)CAP * IIMG, IIMG,
        counts, toks, wtsp, 8, out);
    k_down<<<dim3(H / NT, CAP / MT, 1), dim3(256), 0, stream>>>(
        swd, H, ISH, 0, hsh, 0, ISH,
        counts, toks, wtsp, 16, out);
}